// Round 1
// baseline (76855.627 us; speedup 1.0000x reference)
//
#include <hip/hip_runtime.h>
#include <stdint.h>

#define B_  256
#define S_  512
#define D_  64
#define H_  256
#define G3_ 768

// ---------------------------------------------------------------------------
// Input-projection GEMM: C[r,g] = sum_k A[rowmap(r),k] * W[g,k] + bias[g]
// rowmap(r) = (r>>chsh)*S_ + t0 + (r & (CH-1))   (rows are (b, t_local) pairs)
// Tile 64x64, 256 threads, 4x4 per thread, K-tile 32, fp32.
// ---------------------------------------------------------------------------
__global__ __launch_bounds__(256) void gemm_in(
    const float* __restrict__ A, const float* __restrict__ W,
    const float* __restrict__ bias, float* __restrict__ C,
    int K, int chsh, int t0)
{
  const int r0 = blockIdx.x * 64;
  const int g0 = blockIdx.y * 64;
  const int tid = threadIdx.x;
  const int tx = tid & 15, ty = tid >> 4;
  const int CHm1 = (1 << chsh) - 1;

  __shared__ float As[64][33];
  __shared__ float Bs[64][33];

  float acc[4][4] = {};

  const int lrow = tid >> 2;          // 64 rows, 4 threads per row
  const int lks  = (tid & 3) << 3;    // 8 floats per thread
  const int r    = r0 + lrow;
  const int rg   = ((r >> chsh) * S_) + t0 + (r & CHm1);
  const float* ap_base = A + (size_t)rg * K + lks;
  const float* wp_base = W + (size_t)(g0 + lrow) * K + lks;

  for (int k0 = 0; k0 < K; k0 += 32) {
    float4 a0 = *(const float4*)(ap_base + k0);
    float4 a1 = *(const float4*)(ap_base + k0 + 4);
    float4 w0 = *(const float4*)(wp_base + k0);
    float4 w1 = *(const float4*)(wp_base + k0 + 4);
    As[lrow][lks+0]=a0.x; As[lrow][lks+1]=a0.y; As[lrow][lks+2]=a0.z; As[lrow][lks+3]=a0.w;
    As[lrow][lks+4]=a1.x; As[lrow][lks+5]=a1.y; As[lrow][lks+6]=a1.z; As[lrow][lks+7]=a1.w;
    Bs[lrow][lks+0]=w0.x; Bs[lrow][lks+1]=w0.y; Bs[lrow][lks+2]=w0.z; Bs[lrow][lks+3]=w0.w;
    Bs[lrow][lks+4]=w1.x; Bs[lrow][lks+5]=w1.y; Bs[lrow][lks+6]=w1.z; Bs[lrow][lks+7]=w1.w;
    __syncthreads();
    #pragma unroll
    for (int kk = 0; kk < 32; ++kk) {
      float a_[4], b_[4];
      #pragma unroll
      for (int i = 0; i < 4; ++i) a_[i] = As[ty*4 + i][kk];
      #pragma unroll
      for (int j = 0; j < 4; ++j) b_[j] = Bs[tx*4 + j][kk];
      #pragma unroll
      for (int i = 0; i < 4; ++i)
        #pragma unroll
        for (int j = 0; j < 4; ++j)
          acc[i][j] += a_[i] * b_[j];
    }
    __syncthreads();
  }

  float4 bi = *(const float4*)&bias[g0 + tx*4];
  #pragma unroll
  for (int i = 0; i < 4; ++i) {
    float4 o;
    o.x = acc[i][0] + bi.x;
    o.y = acc[i][1] + bi.y;
    o.z = acc[i][2] + bi.z;
    o.w = acc[i][3] + bi.w;
    *(float4*)&C[(size_t)(r0 + ty*4 + i) * G3_ + g0 + tx*4] = o;
  }
}

// ---------------------------------------------------------------------------
// Persistent GRU scan over CH steps. Grid = 256 WGs = 16 batch-groups x 16
// unit-tiles. Group g = bid & 15 -> its 16 WGs share bid%8 (same-XCD
// heuristic). Each WG: batch rows [16g,16g+16), hidden units [16u,16u+16).
// W_hh slice (48 rows x 256) staged once in LDS; h tile staged per step.
// Per-batch-group spin barrier on a monotonic counter; h double-buffered.
// ---------------------------------------------------------------------------
__global__ __launch_bounds__(256) void gru_scan(
    const float* __restrict__ gx, const float* __restrict__ Whh,
    const float* __restrict__ bhh, float* __restrict__ hbuf,
    float* __restrict__ y, unsigned* __restrict__ ctr,
    int CH, int t0, int last)
{
  const int bid = blockIdx.x;
  const int g = bid & 15;   // batch group
  const int u = bid >> 4;   // unit tile
  const int b0 = g << 4, j0 = u << 4;
  const int tid = threadIdx.x;
  const int bb = tid >> 4, jj = tid & 15;

  __shared__ float Wl[48][260];  // rows: gate*16 + j_local; pad 260 for b128 + banks
  __shared__ float hs[16][260];

  // Stage W_hh slice: rows {j0..j0+15} for gates r,z,n
  for (int idx = tid; idx < 48 * 64; idx += 256) {
    int row = idx >> 6;
    int k4  = (idx & 63) << 2;
    int gate = row >> 4;
    int jr   = row & 15;
    float4 w = *(const float4*)&Whh[(size_t)(gate * H_ + j0 + jr) * H_ + k4];
    *(float4*)&Wl[row][k4] = w;
  }
  const float bhr = bhh[0 * H_ + j0 + jj];
  const float bhz = bhh[1 * H_ + j0 + jj];
  const float bhn = bhh[2 * H_ + j0 + jj];
  __syncthreads();

  for (int t = 0; t < CH; ++t) {
    // stage h tile (16 rows x 256) from current buffer
    const float* hcur = hbuf + ((t & 1) ? (B_ * H_) : 0);
    for (int idx = tid; idx < 16 * 64; idx += 256) {
      int row = idx >> 6;
      int k4  = (idx & 63) << 2;
      float4 hv = *(const float4*)&hcur[(size_t)(b0 + row) * H_ + k4];
      *(float4*)&hs[row][k4] = hv;
    }
    __syncthreads();

    float ar = 0.f, az = 0.f, an = 0.f;
    #pragma unroll 8
    for (int k = 0; k < H_; k += 4) {
      float4 h4 = *(const float4*)&hs[bb][k];
      float4 wr = *(const float4*)&Wl[jj][k];
      float4 wz = *(const float4*)&Wl[16 + jj][k];
      float4 wn = *(const float4*)&Wl[32 + jj][k];
      ar += h4.x*wr.x + h4.y*wr.y + h4.z*wr.z + h4.w*wr.w;
      az += h4.x*wz.x + h4.y*wz.y + h4.z*wz.z + h4.w*wz.w;
      an += h4.x*wn.x + h4.y*wn.y + h4.z*wn.z + h4.w*wn.w;
    }

    const int b = b0 + bb;
    const float* gxp = gx + (size_t)(b * CH + t) * G3_ + j0 + jj;
    const float xr = gxp[0];
    const float xz = gxp[H_];
    const float xn = gxp[2 * H_];
    const float rr = 1.f / (1.f + expf(-(xr + ar + bhr)));
    const float zz = 1.f / (1.f + expf(-(xz + az + bhz)));
    const float nn = tanhf(xn + rr * (an + bhn));
    const float hprev = hs[bb][j0 + jj];
    const float hnew  = (1.f - zz) * nn + zz * hprev;

    float* hnx = hbuf + (((t + 1) & 1) ? (B_ * H_) : 0);
    hnx[(size_t)b * H_ + j0 + jj] = hnew;
    if (!last) y[((size_t)b * S_ + t0 + t) * H_ + j0 + jj] = hnew;

    if (t + 1 < CH) {
      __threadfence();     // release h_new device-wide
      __syncthreads();     // all threads of WG done
      if (tid == 0) {
        atomicAdd(&ctr[g], 1u);
        const unsigned target = (unsigned)(16 * (t + 1));
        while (__hip_atomic_load(&ctr[g], __ATOMIC_ACQUIRE,
                                 __HIP_MEMORY_SCOPE_AGENT) < target) {}
      }
      __syncthreads();
      __threadfence();     // acquire: L1 invalidate before re-reading hbuf
    }
  }
}

// ---------------------------------------------------------------------------
// Head: LayerNorm(h_last) -> MLP 256->32 (ReLU) -> 32->1. One wave per batch.
// ---------------------------------------------------------------------------
__global__ __launch_bounds__(64) void head_kernel(
    const float* __restrict__ hlast, const float* __restrict__ lng,
    const float* __restrict__ lnb, const float* __restrict__ W1,
    const float* __restrict__ b1, const float* __restrict__ W2,
    const float* __restrict__ b2, float* __restrict__ out)
{
  const int b = blockIdx.x;
  const int lane = threadIdx.x;
  float4 v = *(const float4*)&hlast[(size_t)b * H_ + lane * 4];
  float s = v.x + v.y + v.z + v.w;
  #pragma unroll
  for (int m = 32; m > 0; m >>= 1) s += __shfl_xor(s, m, 64);
  const float mu = s * (1.f / 256.f);
  const float dx = v.x - mu, dy = v.y - mu, dz = v.z - mu, dw = v.w - mu;
  float q = dx*dx + dy*dy + dz*dz + dw*dw;
  #pragma unroll
  for (int m = 32; m > 0; m >>= 1) q += __shfl_xor(q, m, 64);
  const float rstd = rsqrtf(q * (1.f / 256.f) + 1e-5f);

  __shared__ float ln[256];
  const int i4 = lane * 4;
  ln[i4 + 0] = dx * rstd * lng[i4 + 0] + lnb[i4 + 0];
  ln[i4 + 1] = dy * rstd * lng[i4 + 1] + lnb[i4 + 1];
  ln[i4 + 2] = dz * rstd * lng[i4 + 2] + lnb[i4 + 2];
  ln[i4 + 3] = dw * rstd * lng[i4 + 3] + lnb[i4 + 3];
  __syncthreads();

  float hd = 0.f;
  if (lane < 32) {
    const float* w = W1 + (size_t)lane * H_;
    float a = 0.f;
    for (int k = 0; k < H_; ++k) a += ln[k] * w[k];
    a += b1[lane];
    hd = fmaxf(a, 0.f) * W2[lane];
  }
  #pragma unroll
  for (int m = 16; m > 0; m >>= 1) hd += __shfl_xor(hd, m, 64);
  if (lane == 0) out[b] = hd + b2[0];
}

// ---------------------------------------------------------------------------
extern "C" void kernel_launch(void* const* d_in, const int* in_sizes, int n_in,
                              void* d_out, int out_size, void* d_ws, size_t ws_size,
                              hipStream_t stream)
{
  const float* x     = (const float*)d_in[0];
  const float* W_ih0 = (const float*)d_in[1];
  const float* W_ihr = (const float*)d_in[2];
  const float* W_hh  = (const float*)d_in[3];
  const float* b_ih  = (const float*)d_in[4];
  const float* b_hh  = (const float*)d_in[5];
  const float* lng   = (const float*)d_in[6];
  const float* lnb   = (const float*)d_in[7];
  const float* W1    = (const float*)d_in[8];
  const float* b1    = (const float*)d_in[9];
  const float* W2    = (const float*)d_in[10];
  const float* b2    = (const float*)d_in[11];
  float* out = (float*)d_out;

  const size_t y_elems = (size_t)B_ * S_ * H_;   // 33.5M floats (134 MB)
  const size_t h_elems = (size_t)2 * B_ * H_;    // double-buffered h

  // Adaptive gx chunk (must be multiple of 64 for GEMM row tiles; <= ws)
  int CH = 512;
  while (CH > 64) {
    size_t need = (y_elems + (size_t)B_ * CH * G3_ + h_elems) * 4 + 4096;
    if (need <= ws_size) break;
    CH >>= 1;
  }
  const int chsh = __builtin_ctz((unsigned)CH);

  float* y      = (float*)d_ws;
  float* gx     = y + y_elems;
  float* hbuf   = gx + (size_t)B_ * CH * G3_;
  unsigned* ctr = (unsigned*)(hbuf + h_elems);

  for (int l = 0; l < 3; ++l) {
    const float* Wih   = (l == 0) ? W_ih0 : (W_ihr + (size_t)(l - 1) * G3_ * H_);
    const int    K     = (l == 0) ? D_ : H_;
    const float* A     = (l == 0) ? x : y;
    const float* Whh_l = W_hh + (size_t)l * G3_ * H_;
    const float* bih_l = b_ih + (size_t)l * G3_;
    const float* bhh_l = b_hh + (size_t)l * G3_;
    const int last = (l == 2) ? 1 : 0;

    hipMemsetAsync(hbuf, 0, h_elems * sizeof(float), stream);  // h0 = 0

    for (int t0 = 0; t0 < S_; t0 += CH) {
      gemm_in<<<dim3((B_ * CH) / 64, G3_ / 64), 256, 0, stream>>>(
          A, Wih, bih_l, gx, K, chsh, t0);
      hipMemsetAsync(ctr, 0, 64, stream);
      void* args[] = { (void*)&gx, (void*)&Whh_l, (void*)&bhh_l, (void*)&hbuf,
                       (void*)&y, (void*)&ctr, (void*)&CH, (void*)&t0,
                       (void*)&last };
      hipLaunchCooperativeKernel((void*)gru_scan, dim3(256), dim3(256),
                                 args, 0, stream);
    }
  }

  head_kernel<<<256, 64, 0, stream>>>(hbuf, lng, lnb, W1, b1, W2, b2, out);
}

// Round 2
// 31569.437 us; speedup vs baseline: 2.4345x; 2.4345x over previous
//
#include <hip/hip_runtime.h>
#include <stdint.h>

#define B_  256
#define S_  512
#define D_  64
#define H_  256
#define G3_ 768

// ---------------------------------------------------------------------------
// Input-projection GEMM: C[r,g] = sum_k A[rowmap(r),k] * W[g,k] + bias[g]
// rowmap(r) = (r>>chsh)*S_ + t0 + (r & (CH-1))   (rows are (b, t_local) pairs)
// Tile 64x64, 256 threads, 4x4 per thread, K-tile 32, fp32.
// ---------------------------------------------------------------------------
__global__ __launch_bounds__(256) void gemm_in(
    const float* __restrict__ A, const float* __restrict__ W,
    const float* __restrict__ bias, float* __restrict__ C,
    int K, int chsh, int t0)
{
  const int r0 = blockIdx.x * 64;
  const int g0 = blockIdx.y * 64;
  const int tid = threadIdx.x;
  const int tx = tid & 15, ty = tid >> 4;
  const int CHm1 = (1 << chsh) - 1;

  __shared__ float As[64][33];
  __shared__ float Bs[64][33];

  float acc[4][4] = {};

  const int lrow = tid >> 2;          // 64 rows, 4 threads per row
  const int lks  = (tid & 3) << 3;    // 8 floats per thread
  const int r    = r0 + lrow;
  const int rg   = ((r >> chsh) * S_) + t0 + (r & CHm1);
  const float* ap_base = A + (size_t)rg * K + lks;
  const float* wp_base = W + (size_t)(g0 + lrow) * K + lks;

  for (int k0 = 0; k0 < K; k0 += 32) {
    float4 a0 = *(const float4*)(ap_base + k0);
    float4 a1 = *(const float4*)(ap_base + k0 + 4);
    float4 w0 = *(const float4*)(wp_base + k0);
    float4 w1 = *(const float4*)(wp_base + k0 + 4);
    As[lrow][lks+0]=a0.x; As[lrow][lks+1]=a0.y; As[lrow][lks+2]=a0.z; As[lrow][lks+3]=a0.w;
    As[lrow][lks+4]=a1.x; As[lrow][lks+5]=a1.y; As[lrow][lks+6]=a1.z; As[lrow][lks+7]=a1.w;
    Bs[lrow][lks+0]=w0.x; Bs[lrow][lks+1]=w0.y; Bs[lrow][lks+2]=w0.z; Bs[lrow][lks+3]=w0.w;
    Bs[lrow][lks+4]=w1.x; Bs[lrow][lks+5]=w1.y; Bs[lrow][lks+6]=w1.z; Bs[lrow][lks+7]=w1.w;
    __syncthreads();
    #pragma unroll
    for (int kk = 0; kk < 32; ++kk) {
      float a_[4], b_[4];
      #pragma unroll
      for (int i = 0; i < 4; ++i) a_[i] = As[ty*4 + i][kk];
      #pragma unroll
      for (int j = 0; j < 4; ++j) b_[j] = Bs[tx*4 + j][kk];
      #pragma unroll
      for (int i = 0; i < 4; ++i)
        #pragma unroll
        for (int j = 0; j < 4; ++j)
          acc[i][j] += a_[i] * b_[j];
    }
    __syncthreads();
  }

  float4 bi = *(const float4*)&bias[g0 + tx*4];
  #pragma unroll
  for (int i = 0; i < 4; ++i) {
    float4 o;
    o.x = acc[i][0] + bi.x;
    o.y = acc[i][1] + bi.y;
    o.z = acc[i][2] + bi.z;
    o.w = acc[i][3] + bi.w;
    *(float4*)&C[(size_t)(r0 + ty*4 + i) * G3_ + g0 + tx*4] = o;
  }
}

// ---------------------------------------------------------------------------
// Pack W_hh [768][256] row-major -> Wpk[k4][g] float4 (k-major), so the scan's
// per-lane W reads are coalesced (lane j -> consecutive g).
// ---------------------------------------------------------------------------
__global__ __launch_bounds__(64) void pack_w(
    const float* __restrict__ Whh, float* __restrict__ Wpk)
{
  const int g  = blockIdx.x;    // 768
  const int k4 = threadIdx.x;   // 64
  float4 v = *(const float4*)&Whh[(size_t)g * H_ + k4 * 4];
  *(float4*)&Wpk[((size_t)k4 * G3_ + g) * 4] = v;
}

// ---------------------------------------------------------------------------
// GRU scan, batch-split: 128 WGs x 512 threads; WG owns batches {2bid,2bid+1}
// and ALL 768 gate rows. h lives in LDS for the whole chunk -> NO inter-WG
// sync, no fences, no cooperative launch. W_hh streamed from L2 each step
// (k-major packed, coalesced). Thread (j = tid&255, half = tid>>8) accumulates
// gates {j, 256+j, 512+j} over k in [128*half, 128*half+128) for both batches;
// partials reduced through LDS; same thread then does gate math for batch
// b0+half, unit j.
// ---------------------------------------------------------------------------
__global__ __launch_bounds__(512) void gru_scan(
    const float* __restrict__ gx, const float* __restrict__ Wpk,
    const float* __restrict__ bhh, float* __restrict__ hbuf,
    float* __restrict__ y, int CH, int t0, int last)
{
  const int bid  = blockIdx.x;     // 128
  const int b0   = bid * 2;
  const int tid  = threadIdx.x;
  const int j    = tid & 255;
  const int half = tid >> 8;

  __shared__ float hs[2][2][256];        // [buf][b][k]
  __shared__ float part[2][3][2][256];   // [half][gate][b][j]

  // init / reload h
  {
    float h0v = (t0 == 0) ? 0.f : hbuf[(size_t)(b0 + half) * H_ + j];
    hs[0][half][j] = h0v;
  }
  const float bhr = bhh[j], bhz = bhh[H_ + j], bhn = bhh[2 * H_ + j];

  // W base pointers for this thread's k-half (float4 slots, stride 768 per k4)
  const float* wr_b = Wpk + ((size_t)(half * 32) * G3_ + j) * 4;
  const float* wz_b = wr_b + H_ * 4;
  const float* wn_b = wr_b + 2 * H_ * 4;

  __syncthreads();

  int cur = 0;
  for (int t = 0; t < CH; ++t) {
    // gx for math phase (batch b0+half, unit j) — hoisted, hides HBM latency
    const float* gxp = gx + ((size_t)(b0 + half) * CH + t) * G3_ + j;
    const float xr = gxp[0];
    const float xz = gxp[H_];
    const float xn = gxp[2 * H_];

    float ar0 = 0.f, ar1 = 0.f, az0 = 0.f, az1 = 0.f, an0 = 0.f, an1 = 0.f;
    const float* hc0 = &hs[cur][0][half * 128];
    const float* hc1 = &hs[cur][1][half * 128];
    #pragma unroll
    for (int k4 = 0; k4 < 32; ++k4) {
      float4 h0 = *(const float4*)&hc0[k4 * 4];          // LDS broadcast
      float4 h1 = *(const float4*)&hc1[k4 * 4];
      float4 wr = *(const float4*)&wr_b[(size_t)k4 * G3_ * 4];
      float4 wz = *(const float4*)&wz_b[(size_t)k4 * G3_ * 4];
      float4 wn = *(const float4*)&wn_b[(size_t)k4 * G3_ * 4];
      ar0 += wr.x*h0.x + wr.y*h0.y + wr.z*h0.z + wr.w*h0.w;
      ar1 += wr.x*h1.x + wr.y*h1.y + wr.z*h1.z + wr.w*h1.w;
      az0 += wz.x*h0.x + wz.y*h0.y + wz.z*h0.z + wz.w*h0.w;
      az1 += wz.x*h1.x + wz.y*h1.y + wz.z*h1.z + wz.w*h1.w;
      an0 += wn.x*h0.x + wn.y*h0.y + wn.z*h0.z + wn.w*h0.w;
      an1 += wn.x*h1.x + wn.y*h1.y + wn.z*h1.z + wn.w*h1.w;
    }

    part[half][0][0][j] = ar0; part[half][0][1][j] = ar1;
    part[half][1][0][j] = az0; part[half][1][1][j] = az1;
    part[half][2][0][j] = an0; part[half][2][1][j] = an1;
    __syncthreads();

    const float ar = part[0][0][half][j] + part[1][0][half][j];
    const float az = part[0][1][half][j] + part[1][1][half][j];
    const float an = part[0][2][half][j] + part[1][2][half][j];

    const float r  = 1.f / (1.f + expf(-(xr + ar + bhr)));
    const float z  = 1.f / (1.f + expf(-(xz + az + bhz)));
    const float n  = tanhf(xn + r * (an + bhn));
    const float hp = hs[cur][half][j];
    const float hn2 = (1.f - z) * n + z * hp;

    hs[cur ^ 1][half][j] = hn2;
    if (!last) y[((size_t)(b0 + half) * S_ + t0 + t) * H_ + j] = hn2;
    if (t == CH - 1) hbuf[(size_t)(b0 + half) * H_ + j] = hn2;

    cur ^= 1;
    __syncthreads();
  }
}

// ---------------------------------------------------------------------------
// Head: LayerNorm(h_last) -> MLP 256->32 (ReLU) -> 32->1. One wave per batch.
// ---------------------------------------------------------------------------
__global__ __launch_bounds__(64) void head_kernel(
    const float* __restrict__ hlast, const float* __restrict__ lng,
    const float* __restrict__ lnb, const float* __restrict__ W1,
    const float* __restrict__ b1, const float* __restrict__ W2,
    const float* __restrict__ b2, float* __restrict__ out)
{
  const int b = blockIdx.x;
  const int lane = threadIdx.x;
  float4 v = *(const float4*)&hlast[(size_t)b * H_ + lane * 4];
  float s = v.x + v.y + v.z + v.w;
  #pragma unroll
  for (int m = 32; m > 0; m >>= 1) s += __shfl_xor(s, m, 64);
  const float mu = s * (1.f / 256.f);
  const float dx = v.x - mu, dy = v.y - mu, dz = v.z - mu, dw = v.w - mu;
  float q = dx*dx + dy*dy + dz*dz + dw*dw;
  #pragma unroll
  for (int m = 32; m > 0; m >>= 1) q += __shfl_xor(q, m, 64);
  const float rstd = rsqrtf(q * (1.f / 256.f) + 1e-5f);

  __shared__ float ln[256];
  const int i4 = lane * 4;
  ln[i4 + 0] = dx * rstd * lng[i4 + 0] + lnb[i4 + 0];
  ln[i4 + 1] = dy * rstd * lng[i4 + 1] + lnb[i4 + 1];
  ln[i4 + 2] = dz * rstd * lng[i4 + 2] + lnb[i4 + 2];
  ln[i4 + 3] = dw * rstd * lng[i4 + 3] + lnb[i4 + 3];
  __syncthreads();

  float hd = 0.f;
  if (lane < 32) {
    const float* w = W1 + (size_t)lane * H_;
    float a = 0.f;
    for (int k = 0; k < H_; ++k) a += ln[k] * w[k];
    a += b1[lane];
    hd = fmaxf(a, 0.f) * W2[lane];
  }
  #pragma unroll
  for (int m = 16; m > 0; m >>= 1) hd += __shfl_xor(hd, m, 64);
  if (lane == 0) out[b] = hd + b2[0];
}

// ---------------------------------------------------------------------------
extern "C" void kernel_launch(void* const* d_in, const int* in_sizes, int n_in,
                              void* d_out, int out_size, void* d_ws, size_t ws_size,
                              hipStream_t stream)
{
  const float* x     = (const float*)d_in[0];
  const float* W_ih0 = (const float*)d_in[1];
  const float* W_ihr = (const float*)d_in[2];
  const float* W_hh  = (const float*)d_in[3];
  const float* b_ih  = (const float*)d_in[4];
  const float* b_hh  = (const float*)d_in[5];
  const float* lng   = (const float*)d_in[6];
  const float* lnb   = (const float*)d_in[7];
  const float* W1    = (const float*)d_in[8];
  const float* b1    = (const float*)d_in[9];
  const float* W2    = (const float*)d_in[10];
  const float* b2    = (const float*)d_in[11];
  float* out = (float*)d_out;

  const size_t y_elems   = (size_t)B_ * S_ * H_;   // 33.5M floats (134 MB)
  const size_t h_elems   = (size_t)B_ * H_;        // 64K floats
  const size_t wpk_elems = (size_t)G3_ * H_;       // 196K floats (768 KB)

  // Adaptive gx chunk (multiple of 64 for GEMM row tiles; fits ws)
  int CH = 512;
  while (CH > 64) {
    size_t need = (y_elems + (size_t)B_ * CH * G3_ + h_elems + wpk_elems) * 4 + 4096;
    if (need <= ws_size) break;
    CH >>= 1;
  }
  const int chsh = __builtin_ctz((unsigned)CH);

  float* y    = (float*)d_ws;
  float* gx   = y + y_elems;
  float* hbuf = gx + (size_t)B_ * CH * G3_;
  float* Wpk  = hbuf + h_elems;

  for (int l = 0; l < 3; ++l) {
    const float* Wih   = (l == 0) ? W_ih0 : (W_ihr + (size_t)(l - 1) * G3_ * H_);
    const int    K     = (l == 0) ? D_ : H_;
    const float* A     = (l == 0) ? x : y;
    const float* Whh_l = W_hh + (size_t)l * G3_ * H_;
    const float* bih_l = b_ih + (size_t)l * G3_;
    const float* bhh_l = b_hh + (size_t)l * G3_;
    const int last = (l == 2) ? 1 : 0;

    pack_w<<<G3_, 64, 0, stream>>>(Whh_l, Wpk);

    for (int t0 = 0; t0 < S_; t0 += CH) {
      gemm_in<<<dim3((B_ * CH) / 64, G3_ / 64), 256, 0, stream>>>(
          A, Wih, bih_l, gx, K, chsh, t0);
      gru_scan<<<128, 512, 0, stream>>>(gx, Wpk, bhh_l, hbuf, y, CH, t0, last);
    }
  }

  head_kernel<<<256, 64, 0, stream>>>(hbuf, lng, lnb, W1, b1, W2, b2, out);
}

// Round 3
// 19639.760 us; speedup vs baseline: 3.9133x; 1.6074x over previous
//
#include <hip/hip_runtime.h>
#include <stdint.h>

#define B_  256
#define S_  512
#define D_  64
#define H_  256
#define G3_ 768

typedef __attribute__((ext_vector_type(8))) short s8v;   // 8 bf16 (4 VGPRs)
typedef __attribute__((ext_vector_type(4))) float f4v;   // MFMA accumulator

__device__ __forceinline__ unsigned short f2bf(float x) {  // RNE truncate
  unsigned u = __float_as_uint(x);
  unsigned r = (u + 0x7fffu + ((u >> 16) & 1u)) >> 16;
  return (unsigned short)r;
}
__device__ __forceinline__ float bf2f(unsigned short s) {
  return __uint_as_float(((unsigned)s) << 16);
}

// ---------------------------------------------------------------------------
// MFMA bf16-split GEMM: C[r,g] = sum_k A[rowmap(r),k]*W[g,k] + bias[g]
// Split x = hi + lo (bf16 each); x*w ~= xh*wh + xl*wh + xh*wl  (fp32-class).
// Tile 64(M) x 64(G), K-step 32, 256 threads = 4 waves; wave w owns M-rows
// [w*16, w*16+16) x all four 16-col G-subtiles. Fragment: lane l reads 8
// contiguous bf16 at row (l&15), k-chunk (l>>4)*8  (verified B^T pattern).
// grid = (gtile, Mtile) so consecutive blocks share the A-tile.
// ---------------------------------------------------------------------------
__global__ __launch_bounds__(256) void gemm_mfma(
    const float* __restrict__ A, const float* __restrict__ W,
    const float* __restrict__ bias, float* __restrict__ C,
    int K, int chsh, int t0)
{
  const int g0 = blockIdx.x * 64;
  const int r0 = blockIdx.y * 64;
  const int tid = threadIdx.x;
  const int w = tid >> 6, l = tid & 63;
  const int fr = l & 15, fq = l >> 4;

  __shared__ unsigned short Ah[64][40], Al[64][40];   // pad 40: bank-balanced
  __shared__ unsigned short Wh[64][40], Wl[64][40];   // row stride 80B (16B-mult)

  f4v acc[4] = {};

  const int row = tid >> 2, q = tid & 3;
  const int CHm1 = (1 << chsh) - 1;
  const int r = r0 + row;
  const int rg = ((r >> chsh) * S_) + t0 + (r & CHm1);
  const float* ap = A + (size_t)rg * K + q * 8;
  const float* wp = W + (size_t)(g0 + row) * K + q * 8;

  for (int k0 = 0; k0 < K; k0 += 32) {
    float4 a0 = *(const float4*)(ap + k0);
    float4 a1 = *(const float4*)(ap + k0 + 4);
    float4 w0 = *(const float4*)(wp + k0);
    float4 w1 = *(const float4*)(wp + k0 + 4);
    __syncthreads();                  // previous step's fragment reads done
    float av[8] = {a0.x,a0.y,a0.z,a0.w,a1.x,a1.y,a1.z,a1.w};
    float wv[8] = {w0.x,w0.y,w0.z,w0.w,w1.x,w1.y,w1.z,w1.w};
    unsigned short ah[8], al_[8], wh[8], wl_[8];
    #pragma unroll
    for (int i = 0; i < 8; ++i) {
      ah[i]  = f2bf(av[i]);  al_[i] = f2bf(av[i] - bf2f(ah[i]));
      wh[i]  = f2bf(wv[i]);  wl_[i] = f2bf(wv[i] - bf2f(wh[i]));
    }
    *(s8v*)&Ah[row][q*8] = *(s8v*)ah;  *(s8v*)&Al[row][q*8] = *(s8v*)al_;
    *(s8v*)&Wh[row][q*8] = *(s8v*)wh;  *(s8v*)&Wl[row][q*8] = *(s8v*)wl_;
    __syncthreads();

    s8v a_hi = *(const s8v*)&Ah[w*16 + fr][fq*8];
    s8v a_lo = *(const s8v*)&Al[w*16 + fr][fq*8];
    #pragma unroll
    for (int c = 0; c < 4; ++c) {
      s8v b_hi = *(const s8v*)&Wh[c*16 + fr][fq*8];
      s8v b_lo = *(const s8v*)&Wl[c*16 + fr][fq*8];
      acc[c] = __builtin_amdgcn_mfma_f32_16x16x32_bf16(a_hi, b_hi, acc[c], 0, 0, 0);
      acc[c] = __builtin_amdgcn_mfma_f32_16x16x32_bf16(a_lo, b_hi, acc[c], 0, 0, 0);
      acc[c] = __builtin_amdgcn_mfma_f32_16x16x32_bf16(a_hi, b_lo, acc[c], 0, 0, 0);
    }
  }

  // Epilogue: C[row=(l>>4)*4+i][col=l&15] per 16x16 subtile (verified layout).
  const int orow = r0 + w * 16 + fq * 4;
  #pragma unroll
  for (int c = 0; c < 4; ++c) {
    const float bi = bias[g0 + c * 16 + fr];
    #pragma unroll
    for (int i = 0; i < 4; ++i) {
      float v = acc[c][i] + bi;
      __builtin_nontemporal_store(v, &C[(size_t)(orow + i) * G3_ + g0 + c * 16 + fr]);
    }
  }
}

// ---------------------------------------------------------------------------
// Pack W_hh [768][256] row-major -> Wpk[k4][g] float4 (k-major) for the scan.
// ---------------------------------------------------------------------------
__global__ __launch_bounds__(64) void pack_w(
    const float* __restrict__ Whh, float* __restrict__ Wpk)
{
  const int g  = blockIdx.x;    // 768
  const int k4 = threadIdx.x;   // 64
  float4 v = *(const float4*)&Whh[(size_t)g * H_ + k4 * 4];
  *(float4*)&Wpk[((size_t)k4 * G3_ + g) * 4] = v;
}

// ---------------------------------------------------------------------------
// GRU scan: 64 WGs x 512 threads; WG owns 4 batches + all 768 gates. h lives
// in LDS across the chunk (no inter-WG sync). W streamed from L2 (k-major,
// coalesced); y/gx use non-temporal ops so W stays L2-resident. Thread
// (j=tid&255, half=tid>>8) accumulates 3 gates x 4 batches over its k-half;
// LDS partial reduce; then handles outputs for batches half*2,half*2+1.
// ---------------------------------------------------------------------------
__global__ __launch_bounds__(512) void gru_scan(
    const float* __restrict__ gx, const float* __restrict__ Wpk,
    const float* __restrict__ bhh, float* __restrict__ hbuf,
    float* __restrict__ y, int CH, int t0, int last)
{
  const int bid  = blockIdx.x;     // 64
  const int b0   = bid * 4;
  const int tid  = threadIdx.x;
  const int j    = tid & 255;
  const int half = tid >> 8;

  __shared__ float hs[2][4][256];        // [buf][b][k]
  __shared__ float part[2][3][4][256];   // [half][gate][b][j]

  for (int e = tid; e < 4 * 256; e += 512) {
    int bb = e >> 8, jj = e & 255;
    hs[0][bb][jj] = (t0 == 0) ? 0.f : hbuf[(size_t)(b0 + bb) * H_ + jj];
  }
  const float bhr = bhh[j], bhz = bhh[H_ + j], bhn = bhh[2 * H_ + j];

  const float* wr_b = Wpk + ((size_t)(half * 32) * G3_ + j) * 4;
  const float* wz_b = wr_b + H_ * 4;
  const float* wn_b = wr_b + 2 * H_ * 4;

  __syncthreads();

  int cur = 0;
  for (int t = 0; t < CH; ++t) {
    // hoisted non-temporal gx loads for this thread's two outputs
    const float* gp0 = gx + ((size_t)(b0 + half * 2)     * CH + t) * G3_ + j;
    const float* gp1 = gx + ((size_t)(b0 + half * 2 + 1) * CH + t) * G3_ + j;
    const float xr0 = __builtin_nontemporal_load(gp0);
    const float xz0 = __builtin_nontemporal_load(gp0 + H_);
    const float xn0 = __builtin_nontemporal_load(gp0 + 2 * H_);
    const float xr1 = __builtin_nontemporal_load(gp1);
    const float xz1 = __builtin_nontemporal_load(gp1 + H_);
    const float xn1 = __builtin_nontemporal_load(gp1 + 2 * H_);

    float a[3][4] = {};
    #pragma unroll 4
    for (int kk = 0; kk < 32; ++kk) {
      float4 wr = *(const float4*)&wr_b[(size_t)kk * G3_ * 4];
      float4 wz = *(const float4*)&wz_b[(size_t)kk * G3_ * 4];
      float4 wn = *(const float4*)&wn_b[(size_t)kk * G3_ * 4];
      #pragma unroll
      for (int bb = 0; bb < 4; ++bb) {
        float4 h4 = *(const float4*)&hs[cur][bb][half * 128 + kk * 4];  // broadcast
        a[0][bb] += wr.x*h4.x + wr.y*h4.y + wr.z*h4.z + wr.w*h4.w;
        a[1][bb] += wz.x*h4.x + wz.y*h4.y + wz.z*h4.z + wz.w*h4.w;
        a[2][bb] += wn.x*h4.x + wn.y*h4.y + wn.z*h4.z + wn.w*h4.w;
      }
    }
    #pragma unroll
    for (int bb = 0; bb < 4; ++bb) {
      part[half][0][bb][j] = a[0][bb];
      part[half][1][bb][j] = a[1][bb];
      part[half][2][bb][j] = a[2][bb];
    }
    __syncthreads();

    #pragma unroll
    for (int o = 0; o < 2; ++o) {
      const int bb = half * 2 + o;
      const float ar = part[0][0][bb][j] + part[1][0][bb][j];
      const float az = part[0][1][bb][j] + part[1][1][bb][j];
      const float an = part[0][2][bb][j] + part[1][2][bb][j];
      const float xr = o ? xr1 : xr0;
      const float xz = o ? xz1 : xz0;
      const float xn = o ? xn1 : xn0;
      const float rr = 1.f / (1.f + expf(-(xr + ar + bhr)));
      const float zz = 1.f / (1.f + expf(-(xz + az + bhz)));
      const float nn = tanhf(xn + rr * (an + bhn));
      const float hp = hs[cur][bb][j];
      const float hnew = (1.f - zz) * nn + zz * hp;
      hs[cur ^ 1][bb][j] = hnew;
      if (!last)
        __builtin_nontemporal_store(hnew,
            &y[((size_t)(b0 + bb) * S_ + t0 + t) * H_ + j]);
      if (t == CH - 1) hbuf[(size_t)(b0 + bb) * H_ + j] = hnew;
    }
    cur ^= 1;
    __syncthreads();
  }
}

// ---------------------------------------------------------------------------
// Head: LayerNorm(h_last) -> MLP 256->32 (ReLU) -> 32->1. One wave per batch.
// ---------------------------------------------------------------------------
__global__ __launch_bounds__(64) void head_kernel(
    const float* __restrict__ hlast, const float* __restrict__ lng,
    const float* __restrict__ lnb, const float* __restrict__ W1,
    const float* __restrict__ b1, const float* __restrict__ W2,
    const float* __restrict__ b2, float* __restrict__ out)
{
  const int b = blockIdx.x;
  const int lane = threadIdx.x;
  float4 v = *(const float4*)&hlast[(size_t)b * H_ + lane * 4];
  float s = v.x + v.y + v.z + v.w;
  #pragma unroll
  for (int m = 32; m > 0; m >>= 1) s += __shfl_xor(s, m, 64);
  const float mu = s * (1.f / 256.f);
  const float dx = v.x - mu, dy = v.y - mu, dz = v.z - mu, dw = v.w - mu;
  float q = dx*dx + dy*dy + dz*dz + dw*dw;
  #pragma unroll
  for (int m = 32; m > 0; m >>= 1) q += __shfl_xor(q, m, 64);
  const float rstd = rsqrtf(q * (1.f / 256.f) + 1e-5f);

  __shared__ float ln[256];
  const int i4 = lane * 4;
  ln[i4 + 0] = dx * rstd * lng[i4 + 0] + lnb[i4 + 0];
  ln[i4 + 1] = dy * rstd * lng[i4 + 1] + lnb[i4 + 1];
  ln[i4 + 2] = dz * rstd * lng[i4 + 2] + lnb[i4 + 2];
  ln[i4 + 3] = dw * rstd * lng[i4 + 3] + lnb[i4 + 3];
  __syncthreads();

  float hd = 0.f;
  if (lane < 32) {
    const float* w = W1 + (size_t)lane * H_;
    float a = 0.f;
    for (int k = 0; k < H_; ++k) a += ln[k] * w[k];
    a += b1[lane];
    hd = fmaxf(a, 0.f) * W2[lane];
  }
  #pragma unroll
  for (int m = 16; m > 0; m >>= 1) hd += __shfl_xor(hd, m, 64);
  if (lane == 0) out[b] = hd + b2[0];
}

// ---------------------------------------------------------------------------
extern "C" void kernel_launch(void* const* d_in, const int* in_sizes, int n_in,
                              void* d_out, int out_size, void* d_ws, size_t ws_size,
                              hipStream_t stream)
{
  const float* x     = (const float*)d_in[0];
  const float* W_ih0 = (const float*)d_in[1];
  const float* W_ihr = (const float*)d_in[2];
  const float* W_hh  = (const float*)d_in[3];
  const float* b_ih  = (const float*)d_in[4];
  const float* b_hh  = (const float*)d_in[5];
  const float* lng   = (const float*)d_in[6];
  const float* lnb   = (const float*)d_in[7];
  const float* W1    = (const float*)d_in[8];
  const float* b1    = (const float*)d_in[9];
  const float* W2    = (const float*)d_in[10];
  const float* b2    = (const float*)d_in[11];
  float* out = (float*)d_out;

  const size_t y_elems   = (size_t)B_ * S_ * H_;
  const size_t h_elems   = (size_t)B_ * H_;
  const size_t wpk_elems = (size_t)G3_ * H_;

  int CH = 512;
  while (CH > 64) {
    size_t need = (y_elems + (size_t)B_ * CH * G3_ + h_elems + wpk_elems) * 4 + 4096;
    if (need <= ws_size) break;
    CH >>= 1;
  }
  const int chsh = __builtin_ctz((unsigned)CH);

  float* y    = (float*)d_ws;
  float* gx   = y + y_elems;
  float* hbuf = gx + (size_t)B_ * CH * G3_;
  float* Wpk  = hbuf + h_elems;

  for (int l = 0; l < 3; ++l) {
    const float* Wih   = (l == 0) ? W_ih0 : (W_ihr + (size_t)(l - 1) * G3_ * H_);
    const int    K     = (l == 0) ? D_ : H_;
    const float* A     = (l == 0) ? x : y;
    const float* Whh_l = W_hh + (size_t)l * G3_ * H_;
    const float* bih_l = b_ih + (size_t)l * G3_;
    const float* bhh_l = b_hh + (size_t)l * G3_;
    const int last = (l == 2) ? 1 : 0;

    pack_w<<<G3_, 64, 0, stream>>>(Whh_l, Wpk);

    for (int t0 = 0; t0 < S_; t0 += CH) {
      gemm_mfma<<<dim3(G3_ / 64, (B_ * CH) / 64), 256, 0, stream>>>(
          A, Wih, bih_l, gx, K, chsh, t0);
      gru_scan<<<64, 512, 0, stream>>>(gx, Wpk, bhh_l, hbuf, y, CH, t0, last);
    }
  }

  head_kernel<<<256, 64, 0, stream>>>(hbuf, lng, lnb, W1, b1, W2, b2, out);
}